// Round 3
// baseline (693.282 us; speedup 1.0000x reference)
//
#include <hip/hip_runtime.h>
#include <hip/hip_bf16.h>

#define DIN 64
#define DH 128
#define EPSF 1e-5f
#define SLOPE 0.1f

// ---------------- graph prep ----------------

__global__ void k_init(float* deg, int* cnt, float* stats, int N){
    int i = blockIdx.x * 256 + threadIdx.x;
    if (i < N){ deg[i] = 1.0f; cnt[i] = 0; }   // self-loop weight 1.0
    if (i < 4 * DH) stats[i] = 0.0f;           // sum0, sq0, sum1, sq1
}

__global__ void k_count(const int* __restrict__ dst, const float* __restrict__ ew,
                        float* deg, int* cnt, int E){
    int e = blockIdx.x * 256 + threadIdx.x;
    if (e < E){
        int d = dst[e];
        atomicAdd(&deg[d], ew[e]);
        atomicAdd(&cnt[d], 1);
    }
}

__global__ void k_dinv(const float* __restrict__ deg, float* dinv, int N){
    int i = blockIdx.x * 256 + threadIdx.x;
    if (i < N){
        float d = deg[i];
        dinv[i] = (d > 0.0f) ? rsqrtf(d) : 0.0f;
    }
}

// single-block exclusive scan of cnt -> rowstart, cursor
__global__ __launch_bounds__(1024) void k_scan(const int* __restrict__ cnt,
                                               int* rowstart, int* cursor, int N){
    __shared__ int lds[1024];
    int t = threadIdx.x;
    int per = (N + 1023) / 1024;
    int s0 = t * per;
    int s1 = s0 + per; if (s1 > N) s1 = N;
    if (s0 > N) s0 = N;
    int local = 0;
    for (int i = s0; i < s1; i++) local += cnt[i];
    lds[t] = local;
    __syncthreads();
    for (int off = 1; off < 1024; off <<= 1){
        int v = lds[t];
        int add = (t >= off) ? lds[t - off] : 0;
        __syncthreads();
        lds[t] = v + add;
        __syncthreads();
    }
    int base = (t > 0) ? lds[t - 1] : 0;   // exclusive prefix
    for (int i = s0; i < s1; i++){
        rowstart[i] = base;
        cursor[i]   = base;
        base += cnt[i];
    }
    if (t == 1023) rowstart[N] = lds[1023];
}

__global__ void k_scatter(const int* __restrict__ src, const int* __restrict__ dst,
                          const float* __restrict__ ew, const float* __restrict__ dinv,
                          int* cursor, int* __restrict__ csrc, float* __restrict__ ccoef, int E){
    int e = blockIdx.x * 256 + threadIdx.x;
    if (e < E){
        int s = src[e], d = dst[e];
        int slot = atomicAdd(&cursor[d], 1);
        csrc[slot]  = s;
        ccoef[slot] = dinv[s] * ew[e] * dinv[d];
    }
}

// ---------------- GEMMs (f32 VALU, activation tile in LDS, weights via L1/L2) ----------------

// h0 = x @ W0 ; res = x @ Wres + bres.  16 rows/block, 256 threads = 256 out cols (128 | 128).
__global__ __launch_bounds__(256) void k_gemm0(const float* __restrict__ x,
        const float* __restrict__ W0, const float* __restrict__ Wres,
        const float* __restrict__ bres, float* __restrict__ h0,
        float* __restrict__ res, int N){
    __shared__ float xs[16 * DIN];              // 4 KB
    int tid = threadIdx.x;
    int row0 = blockIdx.x * 16;
    for (int i = tid; i < 16 * DIN; i += 256){
        int r = i >> 6, k = i & 63;
        int rr = row0 + r; if (rr >= N) rr = N - 1;
        xs[i] = x[(size_t)rr * DIN + k];
    }
    __syncthreads();
    int c = tid & 127;
    const float* __restrict__ W = (tid < DH) ? W0 : Wres;
    float acc[16];
    #pragma unroll
    for (int r = 0; r < 16; r++) acc[r] = 0.0f;
    for (int k = 0; k < DIN; k++){
        float wk = W[k * DH + c];
        #pragma unroll
        for (int r = 0; r < 16; r++) acc[r] += xs[r * DIN + k] * wk;
    }
    if (tid < DH){
        for (int r = 0; r < 16; r++)
            if (row0 + r < N) h0[(size_t)(row0 + r) * DH + c] = acc[r];
    } else {
        float bb = bres[c];
        for (int r = 0; r < 16; r++)
            if (row0 + r < N) res[(size_t)(row0 + r) * DH + c] = acc[r] + bb;
    }
}

// hout = hin @ W1, K=128, 128 cols. 16 rows/block, 256 threads (2 row-groups x 128 cols).
__global__ __launch_bounds__(256) void k_gemm1(const float* __restrict__ hin,
        const float* __restrict__ W1, float* __restrict__ hout, int N){
    __shared__ float xs[16 * DH];               // 8 KB
    int tid = threadIdx.x;
    int row0 = blockIdx.x * 16;
    for (int i = tid; i < 16 * DH; i += 256){
        int r = i >> 7;
        xs[i] = (row0 + r < N) ? hin[(size_t)row0 * DH + i] : 0.0f;
    }
    __syncthreads();
    int c = tid & 127, rg = tid >> 7;
    float acc[8];
    #pragma unroll
    for (int r = 0; r < 8; r++) acc[r] = 0.0f;
    for (int k = 0; k < DH; k++){
        float wk = W1[k * DH + c];
        #pragma unroll
        for (int r = 0; r < 8; r++) acc[r] += xs[(rg + 2 * r) * DH + k] * wk;
    }
    #pragma unroll
    for (int r = 0; r < 8; r++){
        int rr = row0 + rg + 2 * r;
        if (rr < N) hout[(size_t)rr * DH + c] = acc[r];
    }
}

// ---------------- aggregation: one wave per node over CSR ----------------

__global__ __launch_bounds__(256) void k_aggregate(const float* __restrict__ hin,
        float* __restrict__ out, const float* __restrict__ bias,
        const float* __restrict__ dinv, const int* __restrict__ rowstart,
        const int* __restrict__ csrc, const float* __restrict__ ccoef, int N){
    int node = blockIdx.x * 4 + (threadIdx.x >> 6);
    int lane = threadIdx.x & 63;
    if (node >= N) return;
    float dn = dinv[node];
    float sc = dn * dn;                       // self-loop coefficient
    int col = 2 * lane;
    float2 h = *(const float2*)&hin[(size_t)node * DH + col];
    float2 acc;
    acc.x = bias[col]     + sc * h.x;
    acc.y = bias[col + 1] + sc * h.y;
    int rs = rowstart[node], re = rowstart[node + 1];
    for (int j = rs; j < re; j++){
        int s = csrc[j];
        float cf = ccoef[j];
        float2 hs = *(const float2*)&hin[(size_t)s * DH + col];
        acc.x += cf * hs.x;
        acc.y += cf * hs.y;
    }
    *(float2*)&out[(size_t)node * DH + col] = acc;
}

// ---------------- batchnorm (train) ----------------

__global__ __launch_bounds__(256) void k_bnstats(const float* __restrict__ h,
        float* sum, float* sq, int N, int rpb){
    __shared__ float ls[256], lq[256];
    int tid = threadIdx.x;
    int c = tid & 127, half = tid >> 7;
    int r0 = blockIdx.x * rpb;
    int r1 = r0 + rpb; if (r1 > N) r1 = N;
    float s = 0.0f, q = 0.0f;
    for (int r = r0 + half; r < r1; r += 2){
        float v = h[(size_t)r * DH + c];
        s += v; q += v * v;
    }
    ls[tid] = s; lq[tid] = q;
    __syncthreads();
    if (half == 0){
        atomicAdd(&sum[c], ls[tid] + ls[tid + 128]);
        atomicAdd(&sq[c],  lq[tid] + lq[tid + 128]);
    }
}

__global__ void k_bnfinal(const float* __restrict__ sum, const float* __restrict__ sq,
        const float* __restrict__ g, const float* __restrict__ be,
        float* scale, float* shift, int N){
    int c = threadIdx.x;
    float invN = 1.0f / (float)N;
    float mean = sum[c] * invN;
    float var  = sq[c] * invN - mean * mean;
    float s = g[c] * rsqrtf(var + EPSF);
    scale[c] = s;
    shift[c] = be[c] - mean * s;
}

// h = leaky(h*scale+shift) + res, in place, float4
__global__ __launch_bounds__(256) void k_apply(float* __restrict__ h, const float* __restrict__ res,
        const float* __restrict__ scale, const float* __restrict__ shift, int n4){
    __shared__ float sc[DH], sh[DH];
    int tid = threadIdx.x;
    if (tid < DH){ sc[tid] = scale[tid]; sh[tid] = shift[tid]; }
    __syncthreads();
    int i = blockIdx.x * 256 + tid;
    if (i >= n4) return;
    int idx = i * 4;
    int c = idx & 127;
    float4 v = *(float4*)&h[idx];
    float4 r = *(const float4*)&res[idx];
    float t;
    t = v.x * sc[c]     + sh[c];     v.x = (t >= 0.0f ? t : SLOPE * t) + r.x;
    t = v.y * sc[c + 1] + sh[c + 1]; v.y = (t >= 0.0f ? t : SLOPE * t) + r.y;
    t = v.z * sc[c + 2] + sh[c + 2]; v.z = (t >= 0.0f ? t : SLOPE * t) + r.z;
    t = v.w * sc[c + 3] + sh[c + 3]; v.w = (t >= 0.0f ? t : SLOPE * t) + r.w;
    *(float4*)&h[idx] = v;
}

// ---------------- final layernorm (wave per row, f32 output) ----------------

__global__ __launch_bounds__(256) void k_layernorm(const float* __restrict__ h,
        float* __restrict__ out, int N){
    int node = blockIdx.x * 4 + (threadIdx.x >> 6);
    int lane = threadIdx.x & 63;
    if (node >= N) return;
    int col = 2 * lane;
    float2 v = *(const float2*)&h[(size_t)node * DH + col];
    float s = v.x + v.y;
    float q = v.x * v.x + v.y * v.y;
    #pragma unroll
    for (int off = 1; off < 64; off <<= 1){
        s += __shfl_xor(s, off, 64);
        q += __shfl_xor(q, off, 64);
    }
    float mean = s * (1.0f / DH);
    float var  = q * (1.0f / DH) - mean * mean;
    float rstd = rsqrtf(var + EPSF);
    float2 o;
    o.x = (v.x - mean) * rstd;
    o.y = (v.y - mean) * rstd;
    *(float2*)&out[(size_t)node * DH + col] = o;
}

// ---------------- launch ----------------

extern "C" void kernel_launch(void* const* d_in, const int* in_sizes, int n_in,
                              void* d_out, int out_size, void* d_ws, size_t ws_size,
                              hipStream_t stream){
    const float* x    = (const float*)d_in[0];
    const int*   src  = (const int*)d_in[1];
    const int*   dst  = (const int*)d_in[2];
    const float* ew   = (const float*)d_in[3];
    const float* W0   = (const float*)d_in[4];
    const float* b0   = (const float*)d_in[5];
    const float* g0   = (const float*)d_in[6];
    const float* be0  = (const float*)d_in[7];
    const float* W1   = (const float*)d_in[8];
    const float* b1   = (const float*)d_in[9];
    const float* g1   = (const float*)d_in[10];
    const float* be1  = (const float*)d_in[11];
    const float* Wres = (const float*)d_in[12];
    const float* bres = (const float*)d_in[13];
    float* out = (float*)d_out;

    int N = in_sizes[0] / DIN;
    int E = in_sizes[1];
    size_t N128 = (size_t)N * DH;

    // workspace layout (floats)
    float* A    = (float*)d_ws;        // gemm outputs (both layers)
    float* B    = A + N128;            // agg0 / hL0 / agg1 / final
    float* R    = B + N128;            // residual
    float* deg  = R + N128;            // [N]
    float* dinv = deg + N;             // [N]
    int*   cnt    = (int*)(dinv + N);  // [N]
    int*   rowst  = cnt + N;           // [N+1]
    int*   cursor = rowst + N + 1;     // [N]
    int*   csrc   = cursor + N;        // [E]
    float* ccoef  = (float*)(csrc + E);// [E]
    float* stats  = ccoef + E;         // 8*DH
    float* sum0 = stats,          *sq0 = stats + DH;
    float* sum1 = stats + 2 * DH, *sq1 = stats + 3 * DH;
    float* scale0 = stats + 4 * DH, *shift0 = stats + 5 * DH;
    float* scale1 = stats + 6 * DH, *shift1 = stats + 7 * DH;

    int nb = (N + 255) / 256;
    int eb = (E + 255) / 256;
    int gb = (N + 15) / 16;
    int ab = (N + 3) / 4;
    int rpb = 250;
    int sb = (N + rpb - 1) / rpb;
    int n4 = (int)(N128 / 4);
    int apb = (n4 + 255) / 256;

    k_init   <<<nb, 256, 0, stream>>>(deg, cnt, stats, N);
    k_count  <<<eb, 256, 0, stream>>>(dst, ew, deg, cnt, E);
    k_dinv   <<<nb, 256, 0, stream>>>(deg, dinv, N);
    k_scan   <<<1, 1024, 0, stream>>>(cnt, rowst, cursor, N);
    k_scatter<<<eb, 256, 0, stream>>>(src, dst, ew, dinv, cursor, csrc, ccoef, E);

    // layer 0
    k_gemm0    <<<gb, 256, 0, stream>>>(x, W0, Wres, bres, A, R, N);
    k_aggregate<<<ab, 256, 0, stream>>>(A, B, b0, dinv, rowst, csrc, ccoef, N);
    k_bnstats  <<<sb, 256, 0, stream>>>(B, sum0, sq0, N, rpb);
    k_bnfinal  <<<1, DH, 0, stream>>>(sum0, sq0, g0, be0, scale0, shift0, N);
    k_apply    <<<apb, 256, 0, stream>>>(B, R, scale0, shift0, n4);

    // layer 1
    k_gemm1    <<<gb, 256, 0, stream>>>(B, W1, A, N);
    k_aggregate<<<ab, 256, 0, stream>>>(A, B, b1, dinv, rowst, csrc, ccoef, N);
    k_bnstats  <<<sb, 256, 0, stream>>>(B, sum1, sq1, N, rpb);
    k_bnfinal  <<<1, DH, 0, stream>>>(sum1, sq1, g1, be1, scale1, shift1, N);
    k_apply    <<<apb, 256, 0, stream>>>(B, R, scale1, shift1, n4);

    k_layernorm<<<ab, 256, 0, stream>>>(B, out, N);
}

// Round 4
// 566.578 us; speedup vs baseline: 1.2236x; 1.2236x over previous
//
#include <hip/hip_runtime.h>
#include <hip/hip_bf16.h>

#define DIN 64
#define DH 128
#define EPSF 1e-5f
#define SLOPE 0.1f

// ---------------- graph prep ----------------

__global__ void k_init(float* deg, int* cnt, float* stats, int N){
    int i = blockIdx.x * 256 + threadIdx.x;
    if (i < N){ deg[i] = 1.0f; cnt[i] = 0; }   // self-loop weight 1.0
    if (i < 4 * DH) stats[i] = 0.0f;           // sum0, sq0, sum1, sq1
}

__global__ void k_count(const int* __restrict__ dst, const float* __restrict__ ew,
                        float* deg, int* cnt, int E){
    int e = blockIdx.x * 256 + threadIdx.x;
    if (e < E){
        int d = dst[e];
        atomicAdd(&deg[d], ew[e]);
        atomicAdd(&cnt[d], 1);
    }
}

// phase 1: per-1024-block exclusive scan of cnt -> rowstart, block totals; fused dinv
__global__ __launch_bounds__(1024) void k_scan1d(const int* __restrict__ cnt,
        const float* __restrict__ deg, float* __restrict__ dinv,
        int* __restrict__ rowstart, int* __restrict__ blocksum, int N){
    __shared__ int lds[1024];
    int t = threadIdx.x;
    int i = blockIdx.x * 1024 + t;
    if (i < N){
        float d = deg[i];
        dinv[i] = (d > 0.0f) ? rsqrtf(d) : 0.0f;
    }
    int v = (i < N) ? cnt[i] : 0;
    lds[t] = v;
    __syncthreads();
    for (int off = 1; off < 1024; off <<= 1){
        int add = (t >= off) ? lds[t - off] : 0;
        __syncthreads();
        lds[t] += add;
        __syncthreads();
    }
    if (i < N) rowstart[i] = lds[t] - v;            // block-local exclusive
    if (t == 1023) blocksum[blockIdx.x] = lds[1023];
}

// phase 2: scan block sums (nb <= 1024), set rowstart[N]
__global__ __launch_bounds__(1024) void k_scan2(int* __restrict__ blocksum,
        int* __restrict__ rowstart, int nb, int N, int E){
    __shared__ int lds[1024];
    int t = threadIdx.x;
    int v = (t < nb) ? blocksum[t] : 0;
    lds[t] = v;
    __syncthreads();
    for (int off = 1; off < 1024; off <<= 1){
        int add = (t >= off) ? lds[t - off] : 0;
        __syncthreads();
        lds[t] += add;
        __syncthreads();
    }
    if (t < nb) blocksum[t] = lds[t] - v;           // exclusive block offsets
    if (t == 0) rowstart[N] = E;
}

// phase 3: add block offsets, init cursor
__global__ __launch_bounds__(1024) void k_scan3(int* __restrict__ rowstart,
        int* __restrict__ cursor, const int* __restrict__ blocksum, int N){
    int i = blockIdx.x * 1024 + threadIdx.x;
    if (i < N){
        int v = rowstart[i] + blocksum[blockIdx.x];
        rowstart[i] = v;
        cursor[i]   = v;
    }
}

__global__ void k_scatter(const int* __restrict__ src, const int* __restrict__ dst,
                          const float* __restrict__ ew, const float* __restrict__ dinv,
                          int* cursor, int* __restrict__ csrc, float* __restrict__ ccoef, int E){
    int e = blockIdx.x * 256 + threadIdx.x;
    if (e < E){
        int s = src[e], d = dst[e];
        int slot = atomicAdd(&cursor[d], 1);
        csrc[slot]  = s;
        ccoef[slot] = dinv[s] * ew[e] * dinv[d];
    }
}

// ---------------- GEMMs (f32 VALU, activation tile in LDS, weights via L1/L2) ----------------

// h0 = x @ W0 ; res = x @ Wres + bres.  16 rows/block, 256 threads = 256 out cols (128 | 128).
__global__ __launch_bounds__(256) void k_gemm0(const float* __restrict__ x,
        const float* __restrict__ W0, const float* __restrict__ Wres,
        const float* __restrict__ bres, float* __restrict__ h0,
        float* __restrict__ res, int N){
    __shared__ float xs[16 * DIN];              // 4 KB
    int tid = threadIdx.x;
    int row0 = blockIdx.x * 16;
    for (int i = tid; i < 16 * DIN; i += 256){
        int r = i >> 6, k = i & 63;
        int rr = row0 + r; if (rr >= N) rr = N - 1;
        xs[i] = x[(size_t)rr * DIN + k];
    }
    __syncthreads();
    int c = tid & 127;
    const float* __restrict__ W = (tid < DH) ? W0 : Wres;
    float acc[16];
    #pragma unroll
    for (int r = 0; r < 16; r++) acc[r] = 0.0f;
    for (int k = 0; k < DIN; k++){
        float wk = W[k * DH + c];
        #pragma unroll
        for (int r = 0; r < 16; r++) acc[r] += xs[r * DIN + k] * wk;
    }
    if (tid < DH){
        for (int r = 0; r < 16; r++)
            if (row0 + r < N) h0[(size_t)(row0 + r) * DH + c] = acc[r];
    } else {
        float bb = bres[c];
        for (int r = 0; r < 16; r++)
            if (row0 + r < N) res[(size_t)(row0 + r) * DH + c] = acc[r] + bb;
    }
}

// A = (leaky(B*scale+shift)+R) @ W1 — BN apply + leaky + residual fused into tile load.
__global__ __launch_bounds__(256) void k_gemm1f(const float* __restrict__ B,
        const float* __restrict__ R, const float* __restrict__ sum,
        const float* __restrict__ sq, const float* __restrict__ g,
        const float* __restrict__ be, const float* __restrict__ W1,
        float* __restrict__ A, int N, float invN){
    __shared__ float xs[16 * DH];               // 8 KB
    __shared__ float sc[DH], sh[DH];
    int tid = threadIdx.x;
    if (tid < DH){
        float mean = sum[tid] * invN;
        float var  = sq[tid] * invN - mean * mean;
        float s = g[tid] * rsqrtf(var + EPSF);
        sc[tid] = s;
        sh[tid] = be[tid] - mean * s;
    }
    __syncthreads();
    int row0 = blockIdx.x * 16;
    for (int i = tid; i < 16 * DH; i += 256){
        int r = i >> 7, k = i & 127;
        int rr = row0 + r;
        float xv = 0.0f;
        if (rr < N){
            float t = B[(size_t)rr * DH + k] * sc[k] + sh[k];
            t = (t >= 0.0f) ? t : SLOPE * t;
            xv = t + R[(size_t)rr * DH + k];
        }
        xs[i] = xv;
    }
    __syncthreads();
    int c = tid & 127, rg = tid >> 7;
    float acc[8];
    #pragma unroll
    for (int r = 0; r < 8; r++) acc[r] = 0.0f;
    for (int k = 0; k < DH; k++){
        float wk = W1[k * DH + c];
        #pragma unroll
        for (int r = 0; r < 8; r++) acc[r] += xs[(rg + 2 * r) * DH + k] * wk;
    }
    #pragma unroll
    for (int r = 0; r < 8; r++){
        int rr = row0 + rg + 2 * r;
        if (rr < N) A[(size_t)rr * DH + c] = acc[r];
    }
}

// ---------------- aggregation: one wave per node over CSR ----------------

__global__ __launch_bounds__(256) void k_aggregate(const float* __restrict__ hin,
        float* __restrict__ out, const float* __restrict__ bias,
        const float* __restrict__ dinv, const int* __restrict__ rowstart,
        const int* __restrict__ csrc, const float* __restrict__ ccoef, int N){
    int node = blockIdx.x * 4 + (threadIdx.x >> 6);
    int lane = threadIdx.x & 63;
    if (node >= N) return;
    float dn = dinv[node];
    float sc = dn * dn;                       // self-loop coefficient
    int col = 2 * lane;
    float2 h = *(const float2*)&hin[(size_t)node * DH + col];
    float2 acc;
    acc.x = bias[col]     + sc * h.x;
    acc.y = bias[col + 1] + sc * h.y;
    int rs = rowstart[node], re = rowstart[node + 1];
    for (int j = rs; j < re; j++){
        int s = csrc[j];
        float cf = ccoef[j];
        float2 hs = *(const float2*)&hin[(size_t)s * DH + col];
        acc.x += cf * hs.x;
        acc.y += cf * hs.y;
    }
    *(float2*)&out[(size_t)node * DH + col] = acc;
}

// ---------------- batchnorm stats ----------------

__global__ __launch_bounds__(256) void k_bnstats(const float* __restrict__ h,
        float* sum, float* sq, int N, int rpb){
    __shared__ float ls[256], lq[256];
    int tid = threadIdx.x;
    int c = tid & 127, half = tid >> 7;
    int r0 = blockIdx.x * rpb;
    int r1 = r0 + rpb; if (r1 > N) r1 = N;
    float s = 0.0f, q = 0.0f;
    for (int r = r0 + half; r < r1; r += 2){
        float v = h[(size_t)r * DH + c];
        s += v; q += v * v;
    }
    ls[tid] = s; lq[tid] = q;
    __syncthreads();
    if (half == 0){
        atomicAdd(&sum[c], ls[tid] + ls[tid + 128]);
        atomicAdd(&sq[c],  lq[tid] + lq[tid + 128]);
    }
}

// ---------------- final: BN apply + leaky + residual + layernorm + store ----------------

__global__ __launch_bounds__(256) void k_lnf(const float* __restrict__ B,
        const float* __restrict__ R, const float* __restrict__ sum,
        const float* __restrict__ sq, const float* __restrict__ g,
        const float* __restrict__ be, float* __restrict__ out, int N, float invN){
    int node = blockIdx.x * 4 + (threadIdx.x >> 6);
    int lane = threadIdx.x & 63;
    if (node >= N) return;
    int col = 2 * lane;
    float2 sm  = *(const float2*)&sum[col];
    float2 sqv = *(const float2*)&sq[col];
    float2 gv  = *(const float2*)&g[col];
    float2 bev = *(const float2*)&be[col];
    float m0 = sm.x * invN, m1 = sm.y * invN;
    float va0 = sqv.x * invN - m0 * m0, va1 = sqv.y * invN - m1 * m1;
    float s0 = gv.x * rsqrtf(va0 + EPSF), s1 = gv.y * rsqrtf(va1 + EPSF);
    float h0 = bev.x - m0 * s0, h1 = bev.y - m1 * s1;
    float2 b = *(const float2*)&B[(size_t)node * DH + col];
    float2 r = *(const float2*)&R[(size_t)node * DH + col];
    float t0 = b.x * s0 + h0; t0 = ((t0 >= 0.0f) ? t0 : SLOPE * t0) + r.x;
    float t1 = b.y * s1 + h1; t1 = ((t1 >= 0.0f) ? t1 : SLOPE * t1) + r.y;
    float s = t0 + t1;
    float q = t0 * t0 + t1 * t1;
    #pragma unroll
    for (int off = 1; off < 64; off <<= 1){
        s += __shfl_xor(s, off, 64);
        q += __shfl_xor(q, off, 64);
    }
    float mean = s * (1.0f / DH);
    float var  = q * (1.0f / DH) - mean * mean;
    float rstd = rsqrtf(var + EPSF);
    float2 o;
    o.x = (t0 - mean) * rstd;
    o.y = (t1 - mean) * rstd;
    *(float2*)&out[(size_t)node * DH + col] = o;
}

// ---------------- launch ----------------

extern "C" void kernel_launch(void* const* d_in, const int* in_sizes, int n_in,
                              void* d_out, int out_size, void* d_ws, size_t ws_size,
                              hipStream_t stream){
    const float* x    = (const float*)d_in[0];
    const int*   src  = (const int*)d_in[1];
    const int*   dst  = (const int*)d_in[2];
    const float* ew   = (const float*)d_in[3];
    const float* W0   = (const float*)d_in[4];
    const float* b0   = (const float*)d_in[5];
    const float* g0   = (const float*)d_in[6];
    const float* be0  = (const float*)d_in[7];
    const float* W1   = (const float*)d_in[8];
    const float* b1   = (const float*)d_in[9];
    const float* g1   = (const float*)d_in[10];
    const float* be1  = (const float*)d_in[11];
    const float* Wres = (const float*)d_in[12];
    const float* bres = (const float*)d_in[13];
    float* out = (float*)d_out;

    int N = in_sizes[0] / DIN;
    int E = in_sizes[1];
    size_t N128 = (size_t)N * DH;
    float invN = 1.0f / (float)N;

    // workspace layout (floats)
    float* A    = (float*)d_ws;        // gemm outputs (both layers)
    float* B    = A + N128;            // agg outputs
    float* R    = B + N128;            // residual
    float* deg  = R + N128;            // [N]
    float* dinv = deg + N;             // [N]
    int*   cnt    = (int*)(dinv + N);  // [N]
    int*   rowst  = cnt + N;           // [N+1]
    int*   cursor = rowst + N + 1;     // [N]
    int*   csrc   = cursor + N;        // [E]
    float* ccoef  = (float*)(csrc + E);// [E]
    float* stats  = ccoef + E;         // 4*DH
    float* sum0 = stats,          *sq0 = stats + DH;
    float* sum1 = stats + 2 * DH, *sq1 = stats + 3 * DH;
    int*   blocksum = (int*)(stats + 4 * DH);  // [ceil(N/1024)]

    int nb  = (N + 255) / 256;
    int eb  = (E + 255) / 256;
    int gb  = (N + 15) / 16;
    int ab  = (N + 3) / 4;
    int kb  = (N + 1023) / 1024;
    int rpb = 250;
    int sb  = (N + rpb - 1) / rpb;

    k_init   <<<nb, 256, 0, stream>>>(deg, cnt, stats, N);
    k_count  <<<eb, 256, 0, stream>>>(dst, ew, deg, cnt, E);
    k_scan1d <<<kb, 1024, 0, stream>>>(cnt, deg, dinv, rowst, blocksum, N);
    k_scan2  <<<1, 1024, 0, stream>>>(blocksum, rowst, kb, N, E);
    k_scan3  <<<kb, 1024, 0, stream>>>(rowst, cursor, blocksum, N);
    k_scatter<<<eb, 256, 0, stream>>>(src, dst, ew, dinv, cursor, csrc, ccoef, E);

    // layer 0
    k_gemm0    <<<gb, 256, 0, stream>>>(x, W0, Wres, bres, A, R, N);
    k_aggregate<<<ab, 256, 0, stream>>>(A, B, b0, dinv, rowst, csrc, ccoef, N);
    k_bnstats  <<<sb, 256, 0, stream>>>(B, sum0, sq0, N, rpb);

    // layer 1 (BN0+leaky+residual fused into gemm1 load)
    k_gemm1f   <<<gb, 256, 0, stream>>>(B, R, sum0, sq0, g0, be0, W1, A, N, invN);
    k_aggregate<<<ab, 256, 0, stream>>>(A, B, b1, dinv, rowst, csrc, ccoef, N);
    k_bnstats  <<<sb, 256, 0, stream>>>(B, sum1, sq1, N, rpb);

    // BN1+leaky+residual + layernorm fused
    k_lnf      <<<ab, 256, 0, stream>>>(B, R, sum1, sq1, g1, be1, out, N, invN);
}

// Round 5
// 481.392 us; speedup vs baseline: 1.4402x; 1.1770x over previous
//
#include <hip/hip_runtime.h>
#include <hip/hip_bf16.h>

#define DIN 64
#define DH 128
#define EPSF 1e-5f
#define SLOPE 0.1f

typedef unsigned short u16;
typedef unsigned int u32;

__device__ __forceinline__ float bf2f(u16 u){
    union { u32 i; float f; } v; v.i = ((u32)u) << 16; return v.f;
}
__device__ __forceinline__ u16 f2bf(float f){
    union { float f; u32 i; } v; v.f = f;
    u32 b = v.i;
    b += 0x7FFFu + ((b >> 16) & 1u);    // round to nearest even
    return (u16)(b >> 16);
}
__device__ __forceinline__ u32 pack2(float a, float b){
    return (u32)f2bf(a) | ((u32)f2bf(b) << 16);
}

// ---------------- graph prep ----------------

__global__ void k_init(float* deg, int* cnt, float* stats, int N){
    int i = blockIdx.x * 256 + threadIdx.x;
    if (i < N){ deg[i] = 1.0f; cnt[i] = 0; }   // self-loop weight 1.0
    if (i < 4 * DH) stats[i] = 0.0f;           // sum0, sq0, sum1, sq1
}

__global__ void k_count(const int* __restrict__ dst, const float* __restrict__ ew,
                        float* deg, int* cnt, int E){
    int e = blockIdx.x * 256 + threadIdx.x;
    if (e < E){
        int d = dst[e];
        atomicAdd(&deg[d], ew[e]);
        atomicAdd(&cnt[d], 1);
    }
}

// phase 1: per-1024-block exclusive scan of cnt -> rowstart, block totals; fused dinv
__global__ __launch_bounds__(1024) void k_scan1d(const int* __restrict__ cnt,
        const float* __restrict__ deg, float* __restrict__ dinv,
        int* __restrict__ rowstart, int* __restrict__ blocksum, int N){
    __shared__ int lds[1024];
    int t = threadIdx.x;
    int i = blockIdx.x * 1024 + t;
    if (i < N){
        float d = deg[i];
        dinv[i] = (d > 0.0f) ? rsqrtf(d) : 0.0f;
    }
    int v = (i < N) ? cnt[i] : 0;
    lds[t] = v;
    __syncthreads();
    for (int off = 1; off < 1024; off <<= 1){
        int add = (t >= off) ? lds[t - off] : 0;
        __syncthreads();
        lds[t] += add;
        __syncthreads();
    }
    if (i < N) rowstart[i] = lds[t] - v;            // block-local exclusive
    if (t == 1023) blocksum[blockIdx.x] = lds[1023];
}

// phase 2: scan block sums (nb <= 1024), set rowstart[N]
__global__ __launch_bounds__(1024) void k_scan2(int* __restrict__ blocksum,
        int* __restrict__ rowstart, int nb, int N, int E){
    __shared__ int lds[1024];
    int t = threadIdx.x;
    int v = (t < nb) ? blocksum[t] : 0;
    lds[t] = v;
    __syncthreads();
    for (int off = 1; off < 1024; off <<= 1){
        int add = (t >= off) ? lds[t - off] : 0;
        __syncthreads();
        lds[t] += add;
        __syncthreads();
    }
    if (t < nb) blocksum[t] = lds[t] - v;           // exclusive block offsets
    if (t == 0) rowstart[N] = E;
}

// phase 3: add block offsets, init cursor
__global__ __launch_bounds__(1024) void k_scan3(int* __restrict__ rowstart,
        int* __restrict__ cursor, const int* __restrict__ blocksum, int N){
    int i = blockIdx.x * 1024 + threadIdx.x;
    if (i < N){
        int v = rowstart[i] + blocksum[blockIdx.x];
        rowstart[i] = v;
        cursor[i]   = v;
    }
}

__global__ void k_scatter(const int* __restrict__ src, const int* __restrict__ dst,
                          const float* __restrict__ ew, const float* __restrict__ dinv,
                          int* cursor, int* __restrict__ csrc, float* __restrict__ ccoef, int E){
    int e = blockIdx.x * 256 + threadIdx.x;
    if (e < E){
        int s = src[e], d = dst[e];
        int slot = atomicAdd(&cursor[d], 1);
        csrc[slot]  = s;
        ccoef[slot] = dinv[s] * ew[e] * dinv[d];
    }
}

// ---------------- GEMMs (f32 VALU, activation tile in LDS, weights via L1/L2) ----------------

// h0 = x @ W0 ; res = x @ Wres + bres.  16 rows/block, 256 threads = 256 out cols (128 | 128).
// Outputs stored bf16.
__global__ __launch_bounds__(256) void k_gemm0(const float* __restrict__ x,
        const float* __restrict__ W0, const float* __restrict__ Wres,
        const float* __restrict__ bres, u16* __restrict__ h0,
        u16* __restrict__ res, int N){
    __shared__ float xs[16 * DIN];              // 4 KB
    int tid = threadIdx.x;
    int row0 = blockIdx.x * 16;
    for (int i = tid; i < 16 * DIN; i += 256){
        int r = i >> 6, k = i & 63;
        int rr = row0 + r; if (rr >= N) rr = N - 1;
        xs[i] = x[(size_t)rr * DIN + k];
    }
    __syncthreads();
    int c = tid & 127;
    const float* __restrict__ W = (tid < DH) ? W0 : Wres;
    float acc[16];
    #pragma unroll
    for (int r = 0; r < 16; r++) acc[r] = 0.0f;
    for (int k = 0; k < DIN; k++){
        float wk = W[k * DH + c];
        #pragma unroll
        for (int r = 0; r < 16; r++) acc[r] += xs[r * DIN + k] * wk;
    }
    if (tid < DH){
        for (int r = 0; r < 16; r++)
            if (row0 + r < N) h0[(size_t)(row0 + r) * DH + c] = f2bf(acc[r]);
    } else {
        float bb = bres[c];
        for (int r = 0; r < 16; r++)
            if (row0 + r < N) res[(size_t)(row0 + r) * DH + c] = f2bf(acc[r] + bb);
    }
}

// A = (leaky(B*scale+shift)+R) @ W1 — BN apply + leaky + residual fused into tile load.
// B, R, A bf16; compute f32.
__global__ __launch_bounds__(256) void k_gemm1f(const u16* __restrict__ B,
        const u16* __restrict__ R, const float* __restrict__ sum,
        const float* __restrict__ sq, const float* __restrict__ g,
        const float* __restrict__ be, const float* __restrict__ W1,
        u16* __restrict__ A, int N, float invN){
    __shared__ float xs[16 * DH];               // 8 KB
    __shared__ float sc[DH], sh[DH];
    int tid = threadIdx.x;
    if (tid < DH){
        float mean = sum[tid] * invN;
        float var  = sq[tid] * invN - mean * mean;
        float s = g[tid] * rsqrtf(var + EPSF);
        sc[tid] = s;
        sh[tid] = be[tid] - mean * s;
    }
    __syncthreads();
    int row0 = blockIdx.x * 16;
    for (int i = tid; i < 16 * DH; i += 256){
        int r = i >> 7, k = i & 127;
        int rr = row0 + r;
        float xv = 0.0f;
        if (rr < N){
            float t = bf2f(B[(size_t)rr * DH + k]) * sc[k] + sh[k];
            t = (t >= 0.0f) ? t : SLOPE * t;
            xv = t + bf2f(R[(size_t)rr * DH + k]);
        }
        xs[i] = xv;
    }
    __syncthreads();
    int c = tid & 127, rg = tid >> 7;
    float acc[8];
    #pragma unroll
    for (int r = 0; r < 8; r++) acc[r] = 0.0f;
    for (int k = 0; k < DH; k++){
        float wk = W1[k * DH + c];
        #pragma unroll
        for (int r = 0; r < 8; r++) acc[r] += xs[(rg + 2 * r) * DH + k] * wk;
    }
    #pragma unroll
    for (int r = 0; r < 8; r++){
        int rr = row0 + rg + 2 * r;
        if (rr < N) A[(size_t)rr * DH + c] = f2bf(acc[r]);
    }
}

// ---------------- aggregation: one wave per node over CSR (bf16 features) ----------------

__global__ __launch_bounds__(256) void k_aggregate(const u16* __restrict__ hin,
        u16* __restrict__ out, const float* __restrict__ bias,
        const float* __restrict__ dinv, const int* __restrict__ rowstart,
        const int* __restrict__ csrc, const float* __restrict__ ccoef, int N){
    int node = blockIdx.x * 4 + (threadIdx.x >> 6);
    int lane = threadIdx.x & 63;
    if (node >= N) return;
    float dn = dinv[node];
    float sc = dn * dn;                       // self-loop coefficient
    int col = 2 * lane;
    u32 hu = *(const u32*)&hin[(size_t)node * DH + col];
    float2 acc;
    acc.x = bias[col]     + sc * bf2f((u16)hu);
    acc.y = bias[col + 1] + sc * bf2f((u16)(hu >> 16));
    int rs = rowstart[node], re = rowstart[node + 1];
    int j = rs;
    for (; j + 1 < re; j += 2){
        int s0 = csrc[j], s1 = csrc[j + 1];
        float c0 = ccoef[j], c1 = ccoef[j + 1];
        u32 u0 = *(const u32*)&hin[(size_t)s0 * DH + col];
        u32 u1 = *(const u32*)&hin[(size_t)s1 * DH + col];
        acc.x += c0 * bf2f((u16)u0) + c1 * bf2f((u16)u1);
        acc.y += c0 * bf2f((u16)(u0 >> 16)) + c1 * bf2f((u16)(u1 >> 16));
    }
    if (j < re){
        int s0 = csrc[j];
        float c0 = ccoef[j];
        u32 u0 = *(const u32*)&hin[(size_t)s0 * DH + col];
        acc.x += c0 * bf2f((u16)u0);
        acc.y += c0 * bf2f((u16)(u0 >> 16));
    }
    *(u32*)&out[(size_t)node * DH + col] = pack2(acc.x, acc.y);
}

// ---------------- batchnorm stats (bf16 input, f32 sums) ----------------

__global__ __launch_bounds__(256) void k_bnstats(const u16* __restrict__ h,
        float* sum, float* sq, int N, int rpb){
    __shared__ float ls[256], lq[256];
    int tid = threadIdx.x;
    int c = tid & 127, half = tid >> 7;
    int r0 = blockIdx.x * rpb;
    int r1 = r0 + rpb; if (r1 > N) r1 = N;
    float s = 0.0f, q = 0.0f;
    for (int r = r0 + half; r < r1; r += 2){
        float v = bf2f(h[(size_t)r * DH + c]);
        s += v; q += v * v;
    }
    ls[tid] = s; lq[tid] = q;
    __syncthreads();
    if (half == 0){
        atomicAdd(&sum[c], ls[tid] + ls[tid + 128]);
        atomicAdd(&sq[c],  lq[tid] + lq[tid + 128]);
    }
}

// ---------------- final: BN apply + leaky + residual + layernorm + store ----------------

__global__ __launch_bounds__(256) void k_lnf(const u16* __restrict__ B,
        const u16* __restrict__ R, const float* __restrict__ sum,
        const float* __restrict__ sq, const float* __restrict__ g,
        const float* __restrict__ be, float* __restrict__ out, int N, float invN){
    int node = blockIdx.x * 4 + (threadIdx.x >> 6);
    int lane = threadIdx.x & 63;
    if (node >= N) return;
    int col = 2 * lane;
    float2 sm  = *(const float2*)&sum[col];
    float2 sqv = *(const float2*)&sq[col];
    float2 gv  = *(const float2*)&g[col];
    float2 bev = *(const float2*)&be[col];
    float m0 = sm.x * invN, m1 = sm.y * invN;
    float va0 = sqv.x * invN - m0 * m0, va1 = sqv.y * invN - m1 * m1;
    float s0 = gv.x * rsqrtf(va0 + EPSF), s1 = gv.y * rsqrtf(va1 + EPSF);
    float h0 = bev.x - m0 * s0, h1 = bev.y - m1 * s1;
    u32 bu = *(const u32*)&B[(size_t)node * DH + col];
    u32 ru = *(const u32*)&R[(size_t)node * DH + col];
    float t0 = bf2f((u16)bu) * s0 + h0;
    t0 = ((t0 >= 0.0f) ? t0 : SLOPE * t0) + bf2f((u16)ru);
    float t1 = bf2f((u16)(bu >> 16)) * s1 + h1;
    t1 = ((t1 >= 0.0f) ? t1 : SLOPE * t1) + bf2f((u16)(ru >> 16));
    float s = t0 + t1;
    float q = t0 * t0 + t1 * t1;
    #pragma unroll
    for (int off = 1; off < 64; off <<= 1){
        s += __shfl_xor(s, off, 64);
        q += __shfl_xor(q, off, 64);
    }
    float mean = s * (1.0f / DH);
    float var  = q * (1.0f / DH) - mean * mean;
    float rstd = rsqrtf(var + EPSF);
    float2 o;
    o.x = (t0 - mean) * rstd;
    o.y = (t1 - mean) * rstd;
    *(float2*)&out[(size_t)node * DH + col] = o;
}

// ---------------- launch ----------------

extern "C" void kernel_launch(void* const* d_in, const int* in_sizes, int n_in,
                              void* d_out, int out_size, void* d_ws, size_t ws_size,
                              hipStream_t stream){
    const float* x    = (const float*)d_in[0];
    const int*   src  = (const int*)d_in[1];
    const int*   dst  = (const int*)d_in[2];
    const float* ew   = (const float*)d_in[3];
    const float* W0   = (const float*)d_in[4];
    const float* b0   = (const float*)d_in[5];
    const float* g0   = (const float*)d_in[6];
    const float* be0  = (const float*)d_in[7];
    const float* W1   = (const float*)d_in[8];
    const float* b1   = (const float*)d_in[9];
    const float* g1   = (const float*)d_in[10];
    const float* be1  = (const float*)d_in[11];
    const float* Wres = (const float*)d_in[12];
    const float* bres = (const float*)d_in[13];
    float* out = (float*)d_out;

    int N = in_sizes[0] / DIN;
    int E = in_sizes[1];
    size_t N128 = (size_t)N * DH;
    float invN = 1.0f / (float)N;

    // workspace layout: bf16 tensors first, then f32/int scratch
    u16* A = (u16*)d_ws;               // gemm outputs (both layers), bf16
    u16* B = A + N128;                 // agg outputs, bf16
    u16* R = B + N128;                 // residual, bf16
    float* deg  = (float*)(R + N128);  // [N]
    float* dinv = deg + N;             // [N]
    int*   cnt    = (int*)(dinv + N);  // [N]
    int*   rowst  = cnt + N;           // [N+1]
    int*   cursor = rowst + N + 1;     // [N]
    int*   csrc   = cursor + N;        // [E]
    float* ccoef  = (float*)(csrc + E);// [E]
    float* stats  = ccoef + E;         // 4*DH
    float* sum0 = stats,          *sq0 = stats + DH;
    float* sum1 = stats + 2 * DH, *sq1 = stats + 3 * DH;
    int*   blocksum = (int*)(stats + 4 * DH);  // [ceil(N/1024)]

    int nb  = (N + 255) / 256;
    int eb  = (E + 255) / 256;
    int gb  = (N + 15) / 16;
    int ab  = (N + 3) / 4;
    int kb  = (N + 1023) / 1024;
    int rpb = 250;
    int sb  = (N + rpb - 1) / rpb;

    k_init   <<<nb, 256, 0, stream>>>(deg, cnt, stats, N);
    k_count  <<<eb, 256, 0, stream>>>(dst, ew, deg, cnt, E);
    k_scan1d <<<kb, 1024, 0, stream>>>(cnt, deg, dinv, rowst, blocksum, N);
    k_scan2  <<<1, 1024, 0, stream>>>(blocksum, rowst, kb, N, E);
    k_scan3  <<<kb, 1024, 0, stream>>>(rowst, cursor, blocksum, N);
    k_scatter<<<eb, 256, 0, stream>>>(src, dst, ew, dinv, cursor, csrc, ccoef, E);

    // layer 0
    k_gemm0    <<<gb, 256, 0, stream>>>(x, W0, Wres, bres, A, R, N);
    k_aggregate<<<ab, 256, 0, stream>>>(A, B, b0, dinv, rowst, csrc, ccoef, N);
    k_bnstats  <<<sb, 256, 0, stream>>>(B, sum0, sq0, N, rpb);

    // layer 1 (BN0+leaky+residual fused into gemm1 load)
    k_gemm1f   <<<gb, 256, 0, stream>>>(B, R, sum0, sq0, g0, be0, W1, A, N, invN);
    k_aggregate<<<ab, 256, 0, stream>>>(A, B, b1, dinv, rowst, csrc, ccoef, N);
    k_bnstats  <<<sb, 256, 0, stream>>>(B, sum1, sq1, N, rpb);

    // BN1+leaky+residual + layernorm fused
    k_lnf      <<<ab, 256, 0, stream>>>(B, R, sum1, sq1, g1, be1, out, N, invN);
}

// Round 6
// 394.391 us; speedup vs baseline: 1.7579x; 1.2206x over previous
//
#include <hip/hip_runtime.h>
#include <hip/hip_bf16.h>

#define DIN 64
#define DH 128
#define EPSF 1e-5f
#define SLOPE 0.1f

typedef unsigned short u16;
typedef unsigned int u32;
typedef unsigned long long u64;

#define FIXS 16777216.0f   // 2^24 fixed-point scale for edge weights

__device__ __forceinline__ float bf2f(u16 u){
    union { u32 i; float f; } v; v.i = ((u32)u) << 16; return v.f;
}
__device__ __forceinline__ u16 f2bf(float f){
    union { float f; u32 i; } v; v.f = f;
    u32 b = v.i;
    b += 0x7FFFu + ((b >> 16) & 1u);    // round to nearest even
    return (u16)(b >> 16);
}
__device__ __forceinline__ u32 pack2(float a, float b){
    return (u32)f2bf(a) | ((u32)f2bf(b) << 16);
}

// ---------------- graph prep ----------------

__global__ void k_init(u64* packed, float* stats, int N){
    int i = blockIdx.x * 256 + threadIdx.x;
    if (i < N) packed[i] = 0ull;
    if (i < 4 * DH) stats[i] = 0.0f;           // sum0, sq0, sum1, sq1
}

// ONE returning u64 atomic per edge: count in bits[40..], fixed-point ew sum in bits[0..40).
// Returned old count == slot-within-row -> slotl[e] (coalesced store).
__global__ void k_count(const int* __restrict__ dst, const float* __restrict__ ew,
                        u64* packed, int* __restrict__ slotl, int E){
    int e = blockIdx.x * 256 + threadIdx.x;
    if (e < E){
        int d = dst[e];
        u64 add = (1ull << 40) | (u64)(u32)__float2int_rn(ew[e] * FIXS);
        u64 old = atomicAdd(&packed[d], add);
        slotl[e] = (int)(old >> 40);
    }
}

// phase 1: per-1024-block exclusive scan of cnt -> rowstart, block totals; fused dinv
__global__ __launch_bounds__(1024) void k_scan1d(const u64* __restrict__ packed,
        float* __restrict__ dinv, int* __restrict__ rowstart,
        int* __restrict__ blocksum, int N){
    __shared__ int lds[1024];
    int t = threadIdx.x;
    int i = blockIdx.x * 1024 + t;
    int v = 0;
    if (i < N){
        u64 p = packed[i];
        float deg = 1.0f + (float)(p & 0xFFFFFFFFFFull) * (1.0f / FIXS);
        dinv[i] = rsqrtf(deg);               // deg >= 1 always (self-loop)
        v = (int)(p >> 40);
    }
    lds[t] = v;
    __syncthreads();
    for (int off = 1; off < 1024; off <<= 1){
        int add = (t >= off) ? lds[t - off] : 0;
        __syncthreads();
        lds[t] += add;
        __syncthreads();
    }
    if (i < N) rowstart[i] = lds[t] - v;            // block-local exclusive
    if (t == 1023) blocksum[blockIdx.x] = lds[1023];
}

// phase 2: scan block sums (nb <= 1024), set rowstart[N]
__global__ __launch_bounds__(1024) void k_scan2(int* __restrict__ blocksum,
        int* __restrict__ rowstart, int nb, int N, int E){
    __shared__ int lds[1024];
    int t = threadIdx.x;
    int v = (t < nb) ? blocksum[t] : 0;
    lds[t] = v;
    __syncthreads();
    for (int off = 1; off < 1024; off <<= 1){
        int add = (t >= off) ? lds[t - off] : 0;
        __syncthreads();
        lds[t] += add;
        __syncthreads();
    }
    if (t < nb) blocksum[t] = lds[t] - v;           // exclusive block offsets
    if (t == 0) rowstart[N] = E;
}

// phase 3: add block offsets
__global__ __launch_bounds__(1024) void k_scan3(int* __restrict__ rowstart,
        const int* __restrict__ blocksum, int N){
    int i = blockIdx.x * 1024 + threadIdx.x;
    if (i < N) rowstart[i] += blocksum[blockIdx.x];
}

// place edge data: slot = rowstart[d] + slotl[e]; NO atomics.
__global__ void k_place(const int* __restrict__ src, const int* __restrict__ dst,
                        const float* __restrict__ ew, const float* __restrict__ dinv,
                        const int* __restrict__ rowst, const int* __restrict__ slotl,
                        u64* __restrict__ edata, int E){
    int e = blockIdx.x * 256 + threadIdx.x;
    if (e < E){
        int s = src[e], d = dst[e];
        union { float f; u32 i; } c;
        c.f = dinv[s] * ew[e] * dinv[d];
        edata[(size_t)rowst[d] + slotl[e]] = (u64)(u32)s | ((u64)c.i << 32);
    }
}

// ---------------- GEMMs (f32 VALU, activation tile in LDS, weights via L1/L2) ----------------

// h0 = x @ W0 ; res = x @ Wres + bres.  16 rows/block, 256 threads = 256 out cols (128 | 128).
// Outputs stored bf16.
__global__ __launch_bounds__(256) void k_gemm0(const float* __restrict__ x,
        const float* __restrict__ W0, const float* __restrict__ Wres,
        const float* __restrict__ bres, u16* __restrict__ h0,
        u16* __restrict__ res, int N){
    __shared__ float xs[16 * DIN];              // 4 KB
    int tid = threadIdx.x;
    int row0 = blockIdx.x * 16;
    for (int i = tid; i < 16 * DIN; i += 256){
        int r = i >> 6, k = i & 63;
        int rr = row0 + r; if (rr >= N) rr = N - 1;
        xs[i] = x[(size_t)rr * DIN + k];
    }
    __syncthreads();
    int c = tid & 127;
    const float* __restrict__ W = (tid < DH) ? W0 : Wres;
    float acc[16];
    #pragma unroll
    for (int r = 0; r < 16; r++) acc[r] = 0.0f;
    for (int k = 0; k < DIN; k++){
        float wk = W[k * DH + c];
        #pragma unroll
        for (int r = 0; r < 16; r++) acc[r] += xs[r * DIN + k] * wk;
    }
    if (tid < DH){
        for (int r = 0; r < 16; r++)
            if (row0 + r < N) h0[(size_t)(row0 + r) * DH + c] = f2bf(acc[r]);
    } else {
        float bb = bres[c];
        for (int r = 0; r < 16; r++)
            if (row0 + r < N) res[(size_t)(row0 + r) * DH + c] = f2bf(acc[r] + bb);
    }
}

// A = (leaky(B*scale+shift)+R) @ W1 — BN apply + leaky + residual fused into tile load.
// B, R, A bf16; compute f32.
__global__ __launch_bounds__(256) void k_gemm1f(const u16* __restrict__ B,
        const u16* __restrict__ R, const float* __restrict__ sum,
        const float* __restrict__ sq, const float* __restrict__ g,
        const float* __restrict__ be, const float* __restrict__ W1,
        u16* __restrict__ A, int N, float invN){
    __shared__ float xs[16 * DH];               // 8 KB
    __shared__ float sc[DH], sh[DH];
    int tid = threadIdx.x;
    if (tid < DH){
        float mean = sum[tid] * invN;
        float var  = sq[tid] * invN - mean * mean;
        float s = g[tid] * rsqrtf(var + EPSF);
        sc[tid] = s;
        sh[tid] = be[tid] - mean * s;
    }
    __syncthreads();
    int row0 = blockIdx.x * 16;
    for (int i = tid; i < 16 * DH; i += 256){
        int r = i >> 7, k = i & 127;
        int rr = row0 + r;
        float xv = 0.0f;
        if (rr < N){
            float t = bf2f(B[(size_t)rr * DH + k]) * sc[k] + sh[k];
            t = (t >= 0.0f) ? t : SLOPE * t;
            xv = t + bf2f(R[(size_t)rr * DH + k]);
        }
        xs[i] = xv;
    }
    __syncthreads();
    int c = tid & 127, rg = tid >> 7;
    float acc[8];
    #pragma unroll
    for (int r = 0; r < 8; r++) acc[r] = 0.0f;
    for (int k = 0; k < DH; k++){
        float wk = W1[k * DH + c];
        #pragma unroll
        for (int r = 0; r < 8; r++) acc[r] += xs[(rg + 2 * r) * DH + k] * wk;
    }
    #pragma unroll
    for (int r = 0; r < 8; r++){
        int rr = row0 + rg + 2 * r;
        if (rr < N) A[(size_t)rr * DH + c] = f2bf(acc[r]);
    }
}

// ---------------- aggregation: one wave per node over CSR (bf16 features, packed edges) ----------------

__global__ __launch_bounds__(256) void k_aggregate(const u16* __restrict__ hin,
        u16* __restrict__ out, const float* __restrict__ bias,
        const float* __restrict__ dinv, const int* __restrict__ rowstart,
        const u64* __restrict__ edata, int N){
    int node = blockIdx.x * 4 + (threadIdx.x >> 6);
    int lane = threadIdx.x & 63;
    if (node >= N) return;
    float dn = dinv[node];
    float sc = dn * dn;                       // self-loop coefficient
    int col = 2 * lane;
    u32 hu = *(const u32*)&hin[(size_t)node * DH + col];
    float2 acc;
    acc.x = bias[col]     + sc * bf2f((u16)hu);
    acc.y = bias[col + 1] + sc * bf2f((u16)(hu >> 16));
    int rs = rowstart[node], re = rowstart[node + 1];
    int j = rs;
    for (; j + 1 < re; j += 2){
        u64 e0 = edata[j], e1 = edata[j + 1];
        union { u32 i; float f; } c0, c1;
        c0.i = (u32)(e0 >> 32); c1.i = (u32)(e1 >> 32);
        u32 u0 = *(const u32*)&hin[(size_t)(u32)e0 * DH + col];
        u32 u1 = *(const u32*)&hin[(size_t)(u32)e1 * DH + col];
        acc.x += c0.f * bf2f((u16)u0) + c1.f * bf2f((u16)u1);
        acc.y += c0.f * bf2f((u16)(u0 >> 16)) + c1.f * bf2f((u16)(u1 >> 16));
    }
    if (j < re){
        u64 e0 = edata[j];
        union { u32 i; float f; } c0;
        c0.i = (u32)(e0 >> 32);
        u32 u0 = *(const u32*)&hin[(size_t)(u32)e0 * DH + col];
        acc.x += c0.f * bf2f((u16)u0);
        acc.y += c0.f * bf2f((u16)(u0 >> 16));
    }
    *(u32*)&out[(size_t)node * DH + col] = pack2(acc.x, acc.y);
}

// ---------------- batchnorm stats (bf16 input via u32 loads, f32 sums) ----------------

__global__ __launch_bounds__(256) void k_bnstats(const u16* __restrict__ h,
        float* sum, float* sq, int N, int rpb){
    __shared__ float rs[4][DH], rq[4][DH];
    int tid = threadIdx.x;
    int lane = tid & 63, wave = tid >> 6;
    int c = 2 * lane;
    int r0 = blockIdx.x * rpb;
    int r1 = r0 + rpb; if (r1 > N) r1 = N;
    float s0 = 0.0f, s1 = 0.0f, q0 = 0.0f, q1 = 0.0f;
    for (int r = r0 + wave; r < r1; r += 4){
        u32 u = *(const u32*)&h[(size_t)r * DH + c];
        float v0 = bf2f((u16)u), v1 = bf2f((u16)(u >> 16));
        s0 += v0; s1 += v1; q0 += v0 * v0; q1 += v1 * v1;
    }
    rs[wave][c] = s0; rs[wave][c + 1] = s1;
    rq[wave][c] = q0; rq[wave][c + 1] = q1;
    __syncthreads();
    if (tid < DH){
        atomicAdd(&sum[tid], rs[0][tid] + rs[1][tid] + rs[2][tid] + rs[3][tid]);
        atomicAdd(&sq[tid],  rq[0][tid] + rq[1][tid] + rq[2][tid] + rq[3][tid]);
    }
}

// ---------------- final: BN apply + leaky + residual + layernorm + store ----------------

__global__ __launch_bounds__(256) void k_lnf(const u16* __restrict__ B,
        const u16* __restrict__ R, const float* __restrict__ sum,
        const float* __restrict__ sq, const float* __restrict__ g,
        const float* __restrict__ be, float* __restrict__ out, int N, float invN){
    int node = blockIdx.x * 4 + (threadIdx.x >> 6);
    int lane = threadIdx.x & 63;
    if (node >= N) return;
    int col = 2 * lane;
    float2 sm  = *(const float2*)&sum[col];
    float2 sqv = *(const float2*)&sq[col];
    float2 gv  = *(const float2*)&g[col];
    float2 bev = *(const float2*)&be[col];
    float m0 = sm.x * invN, m1 = sm.y * invN;
    float va0 = sqv.x * invN - m0 * m0, va1 = sqv.y * invN - m1 * m1;
    float s0 = gv.x * rsqrtf(va0 + EPSF), s1 = gv.y * rsqrtf(va1 + EPSF);
    float h0 = bev.x - m0 * s0, h1 = bev.y - m1 * s1;
    u32 bu = *(const u32*)&B[(size_t)node * DH + col];
    u32 ru = *(const u32*)&R[(size_t)node * DH + col];
    float t0 = bf2f((u16)bu) * s0 + h0;
    t0 = ((t0 >= 0.0f) ? t0 : SLOPE * t0) + bf2f((u16)ru);
    float t1 = bf2f((u16)(bu >> 16)) * s1 + h1;
    t1 = ((t1 >= 0.0f) ? t1 : SLOPE * t1) + bf2f((u16)(ru >> 16));
    float s = t0 + t1;
    float q = t0 * t0 + t1 * t1;
    #pragma unroll
    for (int off = 1; off < 64; off <<= 1){
        s += __shfl_xor(s, off, 64);
        q += __shfl_xor(q, off, 64);
    }
    float mean = s * (1.0f / DH);
    float var  = q * (1.0f / DH) - mean * mean;
    float rstd = rsqrtf(var + EPSF);
    float2 o;
    o.x = (t0 - mean) * rstd;
    o.y = (t1 - mean) * rstd;
    *(float2*)&out[(size_t)node * DH + col] = o;
}

// ---------------- launch ----------------

extern "C" void kernel_launch(void* const* d_in, const int* in_sizes, int n_in,
                              void* d_out, int out_size, void* d_ws, size_t ws_size,
                              hipStream_t stream){
    const float* x    = (const float*)d_in[0];
    const int*   src  = (const int*)d_in[1];
    const int*   dst  = (const int*)d_in[2];
    const float* ew   = (const float*)d_in[3];
    const float* W0   = (const float*)d_in[4];
    const float* b0   = (const float*)d_in[5];
    const float* g0   = (const float*)d_in[6];
    const float* be0  = (const float*)d_in[7];
    const float* W1   = (const float*)d_in[8];
    const float* b1   = (const float*)d_in[9];
    const float* g1   = (const float*)d_in[10];
    const float* be1  = (const float*)d_in[11];
    const float* Wres = (const float*)d_in[12];
    const float* bres = (const float*)d_in[13];
    float* out = (float*)d_out;

    int N = in_sizes[0] / DIN;
    int E = in_sizes[1];
    size_t N128 = (size_t)N * DH;
    float invN = 1.0f / (float)N;

    // workspace layout
    u16* A = (u16*)d_ws;               // gemm outputs (both layers), bf16 [N128]
    u16* B = A + N128;                 // agg outputs, bf16 [N128]
    u16* R = B + N128;                 // residual, bf16 [N128]
    u64* packed = (u64*)(R + N128);    // [N] count<<40 | fixed ew sum  (8B aligned: N128*2B*3 = 38.4MB, mult of 8)
    u64* edata  = packed + N;          // [E] src | coef<<32
    float* dinv = (float*)(edata + E); // [N]
    int* rowst  = (int*)(dinv + N);    // [N+1]
    int* slotl  = rowst + N + 1;       // [E]
    float* stats = (float*)(slotl + E);// 4*DH
    float* sum0 = stats,          *sq0 = stats + DH;
    float* sum1 = stats + 2 * DH, *sq1 = stats + 3 * DH;
    int* blocksum = (int*)(stats + 4 * DH);  // [ceil(N/1024)]

    int nb  = (N + 255) / 256;
    int eb  = (E + 255) / 256;
    int gb  = (N + 15) / 16;
    int ab  = (N + 3) / 4;
    int kb  = (N + 1023) / 1024;
    int rpb = 250;
    int sb  = (N + rpb - 1) / rpb;

    k_init   <<<nb, 256, 0, stream>>>(packed, stats, N);
    k_count  <<<eb, 256, 0, stream>>>(dst, ew, packed, slotl, E);
    k_scan1d <<<kb, 1024, 0, stream>>>(packed, dinv, rowst, blocksum, N);
    k_scan2  <<<1, 1024, 0, stream>>>(blocksum, rowst, kb, N, E);
    k_scan3  <<<kb, 1024, 0, stream>>>(rowst, blocksum, N);
    k_place  <<<eb, 256, 0, stream>>>(src, dst, ew, dinv, rowst, slotl, edata, E);

    // layer 0
    k_gemm0    <<<gb, 256, 0, stream>>>(x, W0, Wres, bres, A, R, N);
    k_aggregate<<<ab, 256, 0, stream>>>(A, B, b0, dinv, rowst, edata, N);
    k_bnstats  <<<sb, 256, 0, stream>>>(B, sum0, sq0, N, rpb);

    // layer 1 (BN0+leaky+residual fused into gemm1 load)
    k_gemm1f   <<<gb, 256, 0, stream>>>(B, R, sum0, sq0, g0, be0, W1, A, N, invN);
    k_aggregate<<<ab, 256, 0, stream>>>(A, B, b1, dinv, rowst, edata, N);
    k_bnstats  <<<sb, 256, 0, stream>>>(B, sum1, sq1, N, rpb);

    // BN1+leaky+residual + layernorm fused
    k_lnf      <<<ab, 256, 0, stream>>>(B, R, sum1, sq1, g1, be1, out, N, invN);
}